// Round 3
// baseline (143.632 us; speedup 1.0000x reference)
//
#include <hip/hip_runtime.h>

#define HH 512
#define WW 512
#define NB 16
#define NTOT (NB * 3 * HH * WW)     // 12582912
#define NGRP (NTOT / 3)             // 4194304
#define LW 72                        // tile row width in LDS (64 + 4 left + 4 right align)
#define LH 10                        // 8 rows + 2 halo below
// tile 64x8, block (16,8)=128 threads, each thread owns 4 consecutive px in a row.
// 12 unique offsets (each appears twice in the reference's 24 with flipped sign;
// di is squared, do is abs'd -> identical contribution -> factor 2 in inv_norm).

__device__ __forceinline__ int floordiv3(int v) {
    return (v >= 0) ? (v / 3) : -((-v + 2) / 3);
}

template<bool EDGE>
__device__ __forceinline__ void run_tile(const float* __restrict__ x,
                                         const float* __restrict__ op,
                                         float* __restrict__ total,
                                         int b, int h0, int w0)
{
    __shared__ alignas(16) float s_y[3][LH][LW];
    __shared__ alignas(16) float s_o[3][LH][LW];
    __shared__ float s_part[2];

    const int tx  = threadIdx.x;          // 0..15
    const int ty  = threadIdx.y;          // 0..7
    const int tid = ty * 16 + tx;

    // ---------- stage output tile: 30 rows x 18 aligned float4 chunks ----------
    for (int t = tid; t < 3 * LH * (LW / 4); t += 128) {   // 540
        const int rr = t / 18;
        const int k  = t - rr * 18;
        const int c  = rr / 10;
        const int r  = rr - c * 10;
        const int fb = ((b * 3 + c) * HH + (h0 + r)) * WW + (w0 - 4);
        int f = fb + 4 * k;
        if (EDGE) f = min(max(f, 0), NTOT - 4);
        *(float4*)&s_o[c][r][4 * k] = *(const float4*)(op + f);
    }

    // ---------- stage ycc tile: one 3-float group per lane-task ----------
    // ycc[f] = x[3g..3g+2] . mat[:,j] + bias[j], g=f/3, j=f%3 (reference's
    // reshape(-1,3) @ mat). Lane writes 3 floats at stride-3 words ->
    // bank-permutation per pass, conflict-free.
    for (int t = tid; t < 3 * LH * 24; t += 128) {         // 720
        const int rr = t / 24;
        const int k  = t - rr * 24;
        const int c  = rr / 10;
        const int r  = rr - c * 10;
        const int fb = ((b * 3 + c) * HH + (h0 + r)) * WW + (w0 - 4);
        const int g0 = EDGE ? floordiv3(fb + 2) : (fb + 2) / 3;
        const int g  = g0 + k;
        const int gm = EDGE ? min(max(g, 0), NGRP - 1) : g;
        const float x0 = x[3 * gm];
        const float x1 = x[3 * gm + 1];
        const float x2 = x[3 * gm + 2];
        const float y0 = fmaf(x0, 0.257f, fmaf(x1, 0.564f, fmaf(x2, 0.098f, 16.f/255.f)));
        const float y1 = fmaf(x0,-0.148f, fmaf(x1,-0.291f, fmaf(x2, 0.439f, 128.f/255.f)));
        const float y2 = fmaf(x0, 0.439f, fmaf(x1,-0.368f, fmaf(x2,-0.071f, 128.f/255.f)));
        const int cu = 3 * g - fb;        // >= 0 by construction of g0
        if (cu     < LW) s_y[c][r][cu]     = y0;
        if (cu + 1 < LW) s_y[c][r][cu + 1] = y1;
        if (cu + 2 < LW) s_y[c][r][cu + 2] = y2;
    }

    __syncthreads();

    // ---------- compute: 4 px per thread at cu = 4*tx+4+p ----------
    const int h  = h0 + ty;
    const int wq = w0 + 4 * tx;

    float by[3][4], bo[3][4], ey[3][2], eo[3][2];
#pragma unroll
    for (int c = 0; c < 3; ++c) {
        float4 v = *(const float4*)&s_y[c][ty][4*tx + 4];
        by[c][0] = v.x; by[c][1] = v.y; by[c][2] = v.z; by[c][3] = v.w;
        v = *(const float4*)&s_o[c][ty][4*tx + 4];
        bo[c][0] = v.x; bo[c][1] = v.y; bo[c][2] = v.z; bo[c][3] = v.w;
        float2 e = *(const float2*)&s_y[c][ty][4*tx + 8];
        ey[c][0] = e.x; ey[c][1] = e.y;
        e = *(const float2*)&s_o[c][ty][4*tx + 8];
        eo[c][0] = e.x; eo[c][1] = e.y;
    }

    constexpr float SC2 = -0.0072134752044448f;  // -1/(2*100) * log2(e)
    float acc = 0.f;

    // ---- dy = 0, dx = 1,2 ----
#pragma unroll
    for (int dx = 1; dx <= 2; ++dx) {
        const float inv = 2.0f / (float)(NB * HH * (WW - dx));
#pragma unroll
        for (int p = 0; p < 4; ++p) {
            const int i = p + dx;
            const float n0 = (i < 4) ? by[0][i] : ey[0][i-4];
            const float n1 = (i < 4) ? by[1][i] : ey[1][i-4];
            const float n2 = (i < 4) ? by[2][i] : ey[2][i-4];
            const float m0 = (i < 4) ? bo[0][i] : eo[0][i-4];
            const float m1 = (i < 4) ? bo[1][i] : eo[1][i-4];
            const float m2 = (i < 4) ? bo[2][i] : eo[2][i-4];
            const float d0 = n0 - by[0][p], d1 = n1 - by[1][p], d2 = n2 - by[2][p];
            const float sad = fabsf(m0 - bo[0][p]) + fabsf(m1 - bo[1][p]) + fabsf(m2 - bo[2][p]);
            float sc = inv;
            if (EDGE) sc = (wq + p + dx < WW) ? inv : 0.f;
            acc = fmaf(sc * exp2f(SC2 * (d0*d0 + d1*d1 + d2*d2)), sad, acc);
        }
    }

    // ---- dy = 1,2; dx = -2..2 ----
#pragma unroll
    for (int dy = 1; dy <= 2; ++dy) {
        const int r2 = ty + dy;
        float hy[3][12], ho[3][12];
#pragma unroll
        for (int c = 0; c < 3; ++c) {
            float4 v = *(const float4*)&s_y[c][r2][4*tx];
            hy[c][0] = v.x; hy[c][1] = v.y; hy[c][2]  = v.z; hy[c][3]  = v.w;
            v = *(const float4*)&s_y[c][r2][4*tx + 4];
            hy[c][4] = v.x; hy[c][5] = v.y; hy[c][6]  = v.z; hy[c][7]  = v.w;
            v = *(const float4*)&s_y[c][r2][4*tx + 8];
            hy[c][8] = v.x; hy[c][9] = v.y; hy[c][10] = v.z; hy[c][11] = v.w;
            v = *(const float4*)&s_o[c][r2][4*tx];
            ho[c][0] = v.x; ho[c][1] = v.y; ho[c][2]  = v.z; ho[c][3]  = v.w;
            v = *(const float4*)&s_o[c][r2][4*tx + 4];
            ho[c][4] = v.x; ho[c][5] = v.y; ho[c][6]  = v.z; ho[c][7]  = v.w;
            v = *(const float4*)&s_o[c][r2][4*tx + 8];
            ho[c][8] = v.x; ho[c][9] = v.y; ho[c][10] = v.z; ho[c][11] = v.w;
        }
        const bool rowOK = !EDGE || ((h + dy) < HH);
#pragma unroll
        for (int dx = -2; dx <= 2; ++dx) {
            const int adx = (dx < 0) ? -dx : dx;
            const float inv = 2.0f / (float)(NB * (HH - dy) * (WW - adx));
#pragma unroll
            for (int p = 0; p < 4; ++p) {
                const float d0 = hy[0][4 + p + dx] - by[0][p];
                const float d1 = hy[1][4 + p + dx] - by[1][p];
                const float d2 = hy[2][4 + p + dx] - by[2][p];
                const float sad = fabsf(ho[0][4 + p + dx] - bo[0][p])
                                + fabsf(ho[1][4 + p + dx] - bo[1][p])
                                + fabsf(ho[2][4 + p + dx] - bo[2][p]);
                float sc = inv;
                if (EDGE) {
                    const int wn = wq + p + dx;
                    sc = (rowOK && wn >= 0 && wn < WW) ? inv : 0.f;
                }
                acc = fmaf(sc * exp2f(SC2 * (d0*d0 + d1*d1 + d2*d2)), sad, acc);
            }
        }
    }

    // ---------- reduction ----------
#pragma unroll
    for (int off = 32; off > 0; off >>= 1)
        acc += __shfl_down(acc, off, 64);

    if ((tid & 63) == 0) s_part[tid >> 6] = acc;
    __syncthreads();
    if (tid == 0) atomicAdd(total, s_part[0] + s_part[1]);
}

__global__ __launch_bounds__(128, 4)
void smooth_interior(const float* __restrict__ x, const float* __restrict__ op,
                     float* __restrict__ total) {
    // bx in [1,6], by in [0,63): no clamps or boundary selects needed
    run_tile<false>(x, op, total, blockIdx.z, blockIdx.y * 8, (blockIdx.x + 1) * 64);
}

__global__ __launch_bounds__(128, 4)
void smooth_edge(const float* __restrict__ x, const float* __restrict__ op,
                 float* __restrict__ total) {
    const int e = blockIdx.x;
    int bx, by;
    if (e < 64)       { bx = 0;            by = e; }
    else if (e < 128) { bx = 7;            by = e - 64; }
    else              { bx = 1 + (e - 128); by = 63; }
    run_tile<true>(x, op, total, blockIdx.z, by * 8, bx * 64);
}

extern "C" void kernel_launch(void* const* d_in, const int* in_sizes, int n_in,
                              void* d_out, int out_size, void* d_ws, size_t ws_size,
                              hipStream_t stream) {
    const float* x  = (const float*)d_in[0];   // "input"  [16,3,512,512] fp32
    const float* op = (const float*)d_in[1];   // "output" [16,3,512,512] fp32
    float* total = (float*)d_out;              // scalar fp32

    hipMemsetAsync(total, 0, sizeof(float), stream);

    dim3 block(16, 8);                               // 128 threads, 4 px/thread
    smooth_interior<<<dim3(6, 63, NB), block, 0, stream>>>(x, op, total);
    smooth_edge<<<dim3(134, 1, NB), block, 0, stream>>>(x, op, total);
}

// Round 4
// 79.717 us; speedup vs baseline: 1.8018x; 1.8018x over previous
//
#include <hip/hip_runtime.h>
#include <hip/hip_fp16.h>

#define HH 512
#define WW 512
#define NB 16
#define NTOT (NB * 3 * HH * WW)     // 12582912 (divisible by 12)

// Tile 128x8 (+2 halo rows, +/-4 halo cols), LDS tiles stored as f16.
// 12 unique offsets (each appears twice in the reference's 24 with flipped
// sign; di is squared, do is abs'd -> identical contribution -> factor 2).

__device__ __forceinline__ int floordiv3(int v) {
    return (v >= 0) ? (v / 3) : -((-v + 2) / 3);
}

__device__ __forceinline__ void up4(const __half* p, float* d) {
    const uint2 v = *(const uint2*)p;
    const float2 f0 = __half22float2(*(const __half2*)&v.x);
    const float2 f1 = __half22float2(*(const __half2*)&v.y);
    d[0] = f0.x; d[1] = f0.y; d[2] = f1.x; d[3] = f1.y;
}

__device__ __forceinline__ void up2(const __half* p, float* d) {
    const float2 f = __half22float2(*(const __half2*)p);
    d[0] = f.x; d[1] = f.y;
}

template<bool EDGE>
__device__ __forceinline__ void run_tile(
        const float* __restrict__ x, const float* __restrict__ op,
        float* __restrict__ total, int b, int h0, int w0,
        __half (&s_y)[3][10][136], __half (&s_o)[3][10][136], float* s_part)
{
    const int tx  = threadIdx.x;          // 0..31
    const int ty  = threadIdx.y;          // 0..7
    const int tid = ty * 32 + tx;

    // ---------- stage output tile: 510 tasks of 8 px (2 float4 -> 1 uint4) ----------
    for (int t = tid; t < 510; t += 256) {
        const int c  = t / 170;
        const int rm = t - c * 170;
        const int r  = rm / 17;
        const int k  = rm - r * 17;
        const int fb = ((b * 3 + c) * HH + (h0 + r)) * WW + (w0 - 4);
        int fa = fb + 8 * k, fc = fb + 8 * k + 4;
        if (EDGE) {
            fa = min(max(fa, 0), NTOT - 4);
            fc = min(max(fc, 0), NTOT - 4);
        }
        const float4 v0 = *(const float4*)(op + fa);
        const float4 v1 = *(const float4*)(op + fc);
        union { uint4 u; __half2 h[4]; } w;
        w.h[0] = __floats2half2_rn(v0.x, v0.y);
        w.h[1] = __floats2half2_rn(v0.z, v0.w);
        w.h[2] = __floats2half2_rn(v1.x, v1.y);
        w.h[3] = __floats2half2_rn(v1.z, v1.w);
        *(uint4*)&s_o[c][r][8 * k] = w.u;
    }

    // ---------- stage ycc tile: group-quad tasks (12 flats = 3 aligned float4) ----------
    // ycc[f] = x[3g..3g+2].mat[:,j] + bias[j], g=f/3, j=f%3 (reference's
    // reshape(-1,3) @ mat). f0 = 12*c4 -> 48B-aligned global bases.
    for (int t = tid; t < 390; t += 256) {
        const int c  = t / 130;
        const int rm = t - c * 130;
        const int r  = rm / 13;
        const int k  = rm - r * 13;
        const int fb = ((b * 3 + c) * HH + (h0 + r)) * WW + (w0 - 4);
        const int qs = EDGE ? floordiv3(fb + 2) : (fb + 2) / 3;
        const int qe = (fb + 133) / 3;
        const int c4 = (qs >> 2) + k;
        if (c4 <= (qe >> 2)) {
            const int f0 = 12 * c4;
            float xv[12];
            if (EDGE) {
                *(float4*)&xv[0] = *(const float4*)(x + min(max(f0,     0), NTOT - 4));
                *(float4*)&xv[4] = *(const float4*)(x + min(max(f0 + 4, 0), NTOT - 4));
                *(float4*)&xv[8] = *(const float4*)(x + min(max(f0 + 8, 0), NTOT - 4));
            } else {
                *(float4*)&xv[0] = *(const float4*)(x + f0);
                *(float4*)&xv[4] = *(const float4*)(x + f0 + 4);
                *(float4*)&xv[8] = *(const float4*)(x + f0 + 8);
            }
            float yv[12];
#pragma unroll
            for (int g = 0; g < 4; ++g) {
                const float x0 = xv[3*g], x1 = xv[3*g+1], x2 = xv[3*g+2];
                yv[3*g+0] = fmaf(x0, 0.257f, fmaf(x1, 0.564f, fmaf(x2, 0.098f, 16.f/255.f)));
                yv[3*g+1] = fmaf(x0,-0.148f, fmaf(x1,-0.291f, fmaf(x2, 0.439f, 128.f/255.f)));
                yv[3*g+2] = fmaf(x0, 0.439f, fmaf(x1,-0.368f, fmaf(x2,-0.071f, 128.f/255.f)));
            }
            const int cu0 = f0 - fb;              // multiple of 4
            if (cu0 >= 0 && cu0 <= 136 - 12) {
                union { uint2 u; __half2 h[2]; } wa, wb, wc;
                wa.h[0] = __floats2half2_rn(yv[0],  yv[1]);
                wa.h[1] = __floats2half2_rn(yv[2],  yv[3]);
                wb.h[0] = __floats2half2_rn(yv[4],  yv[5]);
                wb.h[1] = __floats2half2_rn(yv[6],  yv[7]);
                wc.h[0] = __floats2half2_rn(yv[8],  yv[9]);
                wc.h[1] = __floats2half2_rn(yv[10], yv[11]);
                *(uint2*)&s_y[c][r][cu0    ] = wa.u;
                *(uint2*)&s_y[c][r][cu0 + 4] = wb.u;
                *(uint2*)&s_y[c][r][cu0 + 8] = wc.u;
            } else {
#pragma unroll
                for (int i = 0; i < 12; ++i) {
                    const int cu = cu0 + i;
                    if (cu >= 0 && cu < 136) s_y[c][r][cu] = __float2half(yv[i]);
                }
            }
        }
    }

    __syncthreads();

    // ---------- compute: 4 px per thread at cu = 4*tx+4+p ----------
    const int h  = h0 + ty;
    const int wq = w0 + 4 * tx;

    float by[3][4], bo[3][4], ey[3][2], eo[3][2];
#pragma unroll
    for (int c = 0; c < 3; ++c) {
        up4(&s_y[c][ty][4*tx + 4], by[c]);
        up4(&s_o[c][ty][4*tx + 4], bo[c]);
        up2(&s_y[c][ty][4*tx + 8], ey[c]);
        up2(&s_o[c][ty][4*tx + 8], eo[c]);
    }

    constexpr float SC2 = -0.0072134752044448f;  // -1/200 * log2(e)
    float acc = 0.f;

    // ---- dy = 0, dx = 1,2 ----
#pragma unroll
    for (int dx = 1; dx <= 2; ++dx) {
        const float inv = 2.0f / (float)(NB * HH * (WW - dx));
#pragma unroll
        for (int p = 0; p < 4; ++p) {
            const int i = p + dx;
            const float n0 = (i < 4) ? by[0][i] : ey[0][i-4];
            const float n1 = (i < 4) ? by[1][i] : ey[1][i-4];
            const float n2 = (i < 4) ? by[2][i] : ey[2][i-4];
            const float m0 = (i < 4) ? bo[0][i] : eo[0][i-4];
            const float m1 = (i < 4) ? bo[1][i] : eo[1][i-4];
            const float m2 = (i < 4) ? bo[2][i] : eo[2][i-4];
            const float d0 = n0 - by[0][p], d1 = n1 - by[1][p], d2 = n2 - by[2][p];
            const float sad = fabsf(m0 - bo[0][p]) + fabsf(m1 - bo[1][p]) + fabsf(m2 - bo[2][p]);
            float sc = inv;
            if (EDGE) sc = (wq + p + dx < WW) ? inv : 0.f;
            acc = fmaf(sc * exp2f(SC2 * (d0*d0 + d1*d1 + d2*d2)), sad, acc);
        }
    }

    // ---- dy = 1,2; dx = -2..2 ----
#pragma unroll
    for (int dy = 1; dy <= 2; ++dy) {
        const int r2 = ty + dy;
        float hy[3][12], ho[3][12];
#pragma unroll
        for (int c = 0; c < 3; ++c) {
            up4(&s_y[c][r2][4*tx    ], &hy[c][0]);
            up4(&s_y[c][r2][4*tx + 4], &hy[c][4]);
            up4(&s_y[c][r2][4*tx + 8], &hy[c][8]);
            up4(&s_o[c][r2][4*tx    ], &ho[c][0]);
            up4(&s_o[c][r2][4*tx + 4], &ho[c][4]);
            up4(&s_o[c][r2][4*tx + 8], &ho[c][8]);
        }
        const bool rowOK = !EDGE || ((h + dy) < HH);
#pragma unroll
        for (int dx = -2; dx <= 2; ++dx) {
            const int adx = (dx < 0) ? -dx : dx;
            const float inv = 2.0f / (float)(NB * (HH - dy) * (WW - adx));
#pragma unroll
            for (int p = 0; p < 4; ++p) {
                const float d0 = hy[0][4 + p + dx] - by[0][p];
                const float d1 = hy[1][4 + p + dx] - by[1][p];
                const float d2 = hy[2][4 + p + dx] - by[2][p];
                const float sad = fabsf(ho[0][4 + p + dx] - bo[0][p])
                                + fabsf(ho[1][4 + p + dx] - bo[1][p])
                                + fabsf(ho[2][4 + p + dx] - bo[2][p]);
                float sc = inv;
                if (EDGE) {
                    const int wn = wq + p + dx;
                    sc = (rowOK && wn >= 0 && wn < WW) ? inv : 0.f;
                }
                acc = fmaf(sc * exp2f(SC2 * (d0*d0 + d1*d1 + d2*d2)), sad, acc);
            }
        }
    }

    // ---------- reduction: wave shuffle -> LDS -> one atomic per block ----------
#pragma unroll
    for (int off = 32; off > 0; off >>= 1)
        acc += __shfl_down(acc, off, 64);

    if ((tid & 63) == 0) s_part[tid >> 6] = acc;
    __syncthreads();
    if (tid == 0)
        atomicAdd(total, s_part[0] + s_part[1] + s_part[2] + s_part[3]);
}

__global__ __launch_bounds__(256)
void smooth_loss_kernel(const float* __restrict__ x, const float* __restrict__ op,
                        float* __restrict__ total)
{
    __shared__ alignas(16) __half s_y[3][10][136];
    __shared__ alignas(16) __half s_o[3][10][136];
    __shared__ float s_part[4];

    const int bx = blockIdx.x, byy = blockIdx.y, b = blockIdx.z;
    const int h0 = byy * 8, w0 = bx * 128;
    // interior: no clamps, no boundary selects (block-uniform branch, one dispatch)
    if ((bx == 1 || bx == 2) && byy < 63)
        run_tile<false>(x, op, total, b, h0, w0, s_y, s_o, s_part);
    else
        run_tile<true>(x, op, total, b, h0, w0, s_y, s_o, s_part);
}

extern "C" void kernel_launch(void* const* d_in, const int* in_sizes, int n_in,
                              void* d_out, int out_size, void* d_ws, size_t ws_size,
                              hipStream_t stream) {
    const float* x  = (const float*)d_in[0];   // "input"  [16,3,512,512] fp32
    const float* op = (const float*)d_in[1];   // "output" [16,3,512,512] fp32
    float* total = (float*)d_out;              // scalar fp32

    hipMemsetAsync(total, 0, sizeof(float), stream);

    dim3 grid(WW / 128, HH / 8, NB);           // 4 x 64 x 16 = 4096 blocks
    dim3 block(32, 8);                         // 256 threads, 4 px/thread
    smooth_loss_kernel<<<grid, block, 0, stream>>>(x, op, total);
}

// Round 5
// 59.630 us; speedup vs baseline: 2.4087x; 1.3369x over previous
//
#include <hip/hip_runtime.h>

#define HH 512
#define WW 512
#define NB 16
#define NTOT (NB * 3 * HH * WW)     // 12582912
#define CHS (HH * WW)               // 262144 (channel stride), 262144 % 3 == 1

// Each thread owns a 4-wide x 8-tall strip. No LDS (except final reduction).
// Rolling register history of 2 previous rows (own 4 cols); current row holds
// 8 cols (own 4 + dx-halo +/-2). ycc built on the fly from a 12-float x window:
// ycc[f] = x[f-j]*mat[0][j] + x[f-j+1]*mat[1][j] + x[f-j+2]*mat[2][j] + bias[j],
// j = f % 3 (faithful to reference's reshape(-1,3) @ mat over flat NCHW).
// 12 unique offsets, each counted twice in the reference -> factor 2 in inv.

#define SC2 (-0.0072134752044448f)  // -1/(2*sigma^2) * log2(e), sigma=10

__device__ __forceinline__ int mod3s(int v) { return v >= 3 ? v - 3 : v; }

__device__ __forceinline__ void load_row(const float* __restrict__ x,
                                         const float* __restrict__ op,
                                         int fbase, int mrow,
                                         float (&yc)[3][8], float (&oc)[3][8])
{
#pragma unroll
    for (int c = 0; c < 3; ++c) {
        const int fb = fbase + c * CHS;
        int mc = mod3s(mrow + c);                  // fb % 3
        const bool m_is[3] = { mc == 0, mc == 1, mc == 2 };
        const int f0 = min(max(fb,     0), NTOT - 4);
        const int f1 = min(max(fb + 4, 0), NTOT - 4);
        const int f2 = min(max(fb + 8, 0), NTOT - 4);
        float xw[12], ow[12];
        *(float4*)&xw[0] = *(const float4*)(x + f0);
        *(float4*)&xw[4] = *(const float4*)(x + f1);
        *(float4*)&xw[8] = *(const float4*)(x + f2);
        *(float4*)&ow[0] = *(const float4*)(op + f0);
        *(float4*)&ow[4] = *(const float4*)(op + f1);
        *(float4*)&ow[8] = *(const float4*)(op + f2);
#pragma unroll
        for (int i = 2; i <= 9; ++i) {
            // candidate per j (group alignment): all static x-window indices
            const float c0 = fmaf(xw[i],    0.257f, fmaf(xw[i+1],  0.564f, fmaf(xw[i+2],  0.098f, 16.f/255.f)));
            const float c1 = fmaf(xw[i-1], -0.148f, fmaf(xw[i],   -0.291f, fmaf(xw[i+1],  0.439f, 128.f/255.f)));
            const float c2 = fmaf(xw[i-2],  0.439f, fmaf(xw[i-1], -0.368f, fmaf(xw[i],   -0.071f, 128.f/255.f)));
            const int t0 = (3 - (i % 3)) % 3;      // j==0  <=>  mc == t0
            const int t1 = (4 - (i % 3)) % 3;      // j==1  <=>  mc == t1
            yc[c][i-2] = m_is[t0] ? c0 : (m_is[t1] ? c1 : c2);
            oc[c][i-2] = ow[i];
        }
    }
}

__device__ __forceinline__ void stash(float (&yb)[3][4], float (&ob)[3][4],
                                      const float (&yc)[3][8], const float (&oc)[3][8])
{
#pragma unroll
    for (int c = 0; c < 3; ++c)
#pragma unroll
        for (int p = 0; p < 4; ++p) { yb[c][p] = yc[c][p+2]; ob[c][p] = oc[c][p+2]; }
}

__device__ __forceinline__ void pairs_dy0(const float (&yc)[3][8], const float (&oc)[3][8],
                                          const bool (&cv)[8], float& acc)
{
#pragma unroll
    for (int dx = 1; dx <= 2; ++dx) {
        const float inv = 2.0f / (float)(NB * HH * (WW - dx));
#pragma unroll
        for (int p = 0; p < 4; ++p) {
            const int k = p + dx + 2, kb = p + 2;
            const float d0 = yc[0][k] - yc[0][kb];
            const float d1 = yc[1][k] - yc[1][kb];
            const float d2 = yc[2][k] - yc[2][kb];
            const float ss = fmaf(d2, d2, fmaf(d1, d1, d0 * d0));
            const float sad = fabsf(oc[0][k] - oc[0][kb]) + fabsf(oc[1][k] - oc[1][kb])
                            + fabsf(oc[2][k] - oc[2][kb]);
            const float sc = cv[k] ? inv : 0.f;
            acc = fmaf(sc * exp2f(SC2 * ss), sad, acc);
        }
    }
}

template<int DY>
__device__ __forceinline__ void pairs_dyn(const float (&yc)[3][8], const float (&oc)[3][8],
                                          const float (&yb)[3][4], const float (&ob)[3][4],
                                          const bool (&cv)[8], float& acc)
{
#pragma unroll
    for (int dx = -2; dx <= 2; ++dx) {
        const int adx = dx < 0 ? -dx : dx;
        const float inv = 2.0f / (float)(NB * (HH - DY) * (WW - adx));
#pragma unroll
        for (int p = 0; p < 4; ++p) {
            const int k = p + dx + 2;              // 0..7
            const float d0 = yc[0][k] - yb[0][p];
            const float d1 = yc[1][k] - yb[1][p];
            const float d2 = yc[2][k] - yb[2][p];
            const float ss = fmaf(d2, d2, fmaf(d1, d1, d0 * d0));
            const float sad = fabsf(oc[0][k] - ob[0][p]) + fabsf(oc[1][k] - ob[1][p])
                            + fabsf(oc[2][k] - ob[2][p]);
            const float sc = cv[k] ? inv : 0.f;
            acc = fmaf(sc * exp2f(SC2 * ss), sad, acc);
        }
    }
}

__global__ __launch_bounds__(256)
void smooth_loss_kernel(const float* __restrict__ x, const float* __restrict__ op,
                        float* __restrict__ total)
{
    const int tx  = threadIdx.x;                    // 0..31
    const int ty  = threadIdx.y;                    // 0..7
    const int tid = ty * 32 + tx;
    const int wq  = blockIdx.x * 128 + 4 * tx;      // first owned col
    const int rb  = blockIdx.y * 64 + 8 * ty;       // first owned row (<= 504)
    const int b   = blockIdx.z;

    // col validity of image col wq-2+k, k=0..7
    bool cv[8];
#pragma unroll
    for (int k = 0; k < 8; ++k) cv[k] = ((unsigned)(wq - 2 + k) < (unsigned)WW);

    const int fb0 = (b * 3 * HH + rb) * WW + (wq - 4);   // c=0, s=0 window base
    int mrow = (2 * rb + wq + 2) % 3;                    // fb0 % 3 (nonneg form)

    float yp[2][3][4], opv[2][3][4];
    float yc[3][8], oc[3][8];
    float acc = 0.f;

    // ---- s = 0 ----
    load_row(x, op, fb0, mrow, yc, oc);
    pairs_dy0(yc, oc, cv, acc);
    stash(yp[0], opv[0], yc, oc);
    // ---- s = 1 ----
    mrow = mod3s(mrow + 2);
    load_row(x, op, fb0 + WW, mrow, yc, oc);
    pairs_dy0(yc, oc, cv, acc);
    pairs_dyn<1>(yc, oc, yp[0], opv[0], cv, acc);
    stash(yp[1], opv[1], yc, oc);

#pragma unroll 1
    for (int s = 2; s < 10; s += 2) {
        // ---- row A = s: slot0 holds s-2, slot1 holds s-1 ----
        mrow = mod3s(mrow + 2);
        const bool rokA = (rb + s) < HH;           // neighbor-row validity
        load_row(x, op, fb0 + s * WW, mrow, yc, oc);
        if (s < 8) pairs_dy0(yc, oc, cv, acc);
        if (rokA) {
            pairs_dyn<1>(yc, oc, yp[1], opv[1], cv, acc);   // base row s-1
            pairs_dyn<2>(yc, oc, yp[0], opv[0], cv, acc);   // base row s-2
        }
        if (s < 8) stash(yp[0], opv[0], yc, oc);
        // ---- row B = s+1: slot0 holds s, slot1 holds s-1 ----
        mrow = mod3s(mrow + 2);
        const bool rokB = (rb + s + 1) < HH;
        load_row(x, op, fb0 + (s + 1) * WW, mrow, yc, oc);
        if (s + 1 < 8) pairs_dy0(yc, oc, cv, acc);
        if (rokB) {
            if (s < 8) pairs_dyn<1>(yc, oc, yp[0], opv[0], cv, acc);  // base row s
            pairs_dyn<2>(yc, oc, yp[1], opv[1], cv, acc);             // base row s-1
        }
        if (s + 1 < 8) stash(yp[1], opv[1], yc, oc);
    }

    // ---- reduction: wave shuffle -> LDS -> one atomic per block ----
#pragma unroll
    for (int off = 32; off > 0; off >>= 1)
        acc += __shfl_down(acc, off, 64);

    __shared__ float s_part[4];
    if ((tid & 63) == 0) s_part[tid >> 6] = acc;
    __syncthreads();
    if (tid == 0)
        atomicAdd(total, s_part[0] + s_part[1] + s_part[2] + s_part[3]);
}

extern "C" void kernel_launch(void* const* d_in, const int* in_sizes, int n_in,
                              void* d_out, int out_size, void* d_ws, size_t ws_size,
                              hipStream_t stream) {
    const float* x  = (const float*)d_in[0];   // "input"  [16,3,512,512] fp32
    const float* op = (const float*)d_in[1];   // "output" [16,3,512,512] fp32
    float* total = (float*)d_out;              // scalar fp32

    hipMemsetAsync(total, 0, sizeof(float), stream);

    dim3 grid(4, 8, NB);                       // 512 blocks
    dim3 block(32, 8);                         // 256 threads; strip 4x8 each
    smooth_loss_kernel<<<grid, block, 0, stream>>>(x, op, total);
}